// Round 17
// baseline (192.641 us; speedup 1.0000x reference)
//
#include <hip/hip_runtime.h>
#include <hip/hip_bf16.h>

#define T_DIM 128
#define S_DIM 128
#define B_DIM 32
#define H_DIM 512
#define C_DIM 512
#define M_DIM 256
#define NEG_BIG -1e8f
#define K2LOG2E 2.8853900817779268f   // 2*log2(e): exp(2x) = exp2(K*x)

typedef __attribute__((ext_vector_type(8))) short shortx8;   // 8 bf16
typedef __attribute__((ext_vector_type(4))) float floatx4;

// f32 -> bf16 RNE, packed pair
__device__ __forceinline__ unsigned bfpair(float a, float b) {
  unsigned ua = __builtin_bit_cast(unsigned, a); ua += 0x7fffu + ((ua >> 16) & 1u);
  unsigned ub = __builtin_bit_cast(unsigned, b); ub += 0x7fffu + ((ub >> 16) & 1u);
  return (ua >> 16) | (ub & 0xffff0000u);
}
__device__ __forceinline__ uint4 pack2(const float4& a, const float4& b) {
  uint4 o;
  o.x = bfpair(a.x, a.y); o.y = bfpair(a.z, a.w);
  o.z = bfpair(b.x, b.y); o.w = bfpair(b.z, b.w);
  return o;
}
__device__ __forceinline__ ushort bf1(float a) {
  unsigned ua = __builtin_bit_cast(unsigned, a); ua += 0x7fffu + ((ua >> 16) & 1u);
  return (ushort)(ua >> 16);
}
// bf16 (packed pair) -> f32 expansion
__device__ __forceinline__ float bflo(unsigned u) { return __builtin_bit_cast(float, u << 16); }
__device__ __forceinline__ float bfhi(unsigned u) { return __builtin_bit_cast(float, u & 0xffff0000u); }
__device__ __forceinline__ float4 expand4(unsigned a, unsigned b) {
  return make_float4(bflo(a), bfhi(a), bflo(b), bfhi(b));
}

// ---------------------------------------------------------------------------
// 64x64 MFMA tile job core, K=512, f32 operands packed to bf16 inline during
// LDS staging. r6-proven: single LDS buffer, 2 barriers per K-step, register
// prefetch between them, coalesced staging, XOR slot swizzle.
// Writes acc[2][2]; caller does the epilogue.
// ---------------------------------------------------------------------------
__device__ __forceinline__ void gemm_core(
    const float* __restrict__ X, const float* __restrict__ W,
    int n0, int m0, ushort* Xs, ushort* Ws, int tid, floatx4 acc[2][2]) {
  const int lane = tid & 63, wave = tid >> 6;
  const int wn = wave & 1, wm = wave >> 1;
  const int l15 = lane & 15, lhi = lane >> 4;
  const int r = tid >> 3, c8 = tid & 7;
  const int sw = (c8 ^ (r & 7)) << 4;         // (r+32)&7 == r&7
  char* xd0 = (char*)Xs + r * 128 + sw;
  char* xd1 = (char*)Xs + (r + 32) * 128 + sw;
  char* wd0 = (char*)Ws + r * 128 + sw;
  char* wd1 = (char*)Ws + (r + 32) * 128 + sw;

  const float* xp0 = X + (size_t)(n0 + r) * 512 + c8 * 8;
  const float* xp1 = X + (size_t)(n0 + r + 32) * 512 + c8 * 8;
  const float* wp0 = W + (size_t)(m0 + r) * 512 + c8 * 8;
  const float* wp1 = W + (size_t)(m0 + r + 32) * 512 + c8 * 8;

  float4 xf0, xf1, xf2, xf3, wf0, wf1, wf2, wf3;
#define LOADXW                                                  \
  xf0 = ((const float4*)xp0)[0]; xf1 = ((const float4*)xp0)[1]; \
  xf2 = ((const float4*)xp1)[0]; xf3 = ((const float4*)xp1)[1]; \
  wf0 = ((const float4*)wp0)[0]; wf1 = ((const float4*)wp0)[1]; \
  wf2 = ((const float4*)wp1)[0]; wf3 = ((const float4*)wp1)[1];
  LOADXW

  for (int it = 0; it < 8; ++it) {
    __syncthreads();   // previous tile's readers done
    *(uint4*)xd0 = pack2(xf0, xf1);
    *(uint4*)xd1 = pack2(xf2, xf3);
    *(uint4*)wd0 = pack2(wf0, wf1);
    *(uint4*)wd1 = pack2(wf2, wf3);
    __syncthreads();
    if (it < 7) {      // prefetch next K-tile; latency hides under MFMA
      xp0 += 64; xp1 += 64; wp0 += 64; wp1 += 64;
      LOADXW
    }
#pragma unroll
    for (int ks = 0; ks < 2; ++ks) {
      const int slotr = lhi + (ks << 2);
      const int sws = ((slotr ^ (l15 & 7)) << 4);
      shortx8 af[2], bfr[2];
#pragma unroll
      for (int fi = 0; fi < 2; ++fi)
        af[fi] = *(const shortx8*)((const char*)Xs + (wn * 32 + fi * 16 + l15) * 128 + sws);
#pragma unroll
      for (int fj = 0; fj < 2; ++fj)
        bfr[fj] = *(const shortx8*)((const char*)Ws + (wm * 32 + fj * 16 + l15) * 128 + sws);
#pragma unroll
      for (int fi = 0; fi < 2; ++fi)
#pragma unroll
        for (int fj = 0; fj < 2; ++fj)
          acc[fi][fj] = __builtin_amdgcn_mfma_f32_16x16x32_bf16(af[fi], bfr[fj], acc[fi][fj], 0, 0, 0);
    }
  }
#undef LOADXW
}

// ---------------------------------------------------------------------------
// k1: EH/EC only (512 blocks, XCD-swizzled):
//   bid [0,256):  EHb (T*B,M) bf16 = exp(2 * hid . Wh^T)
//   bid [256,512): ECb (S*B,M) bf16 = exp(2 * ctx . Wc^T)
// ---------------------------------------------------------------------------
__global__ __launch_bounds__(256) void gemm_ehec(
    const float* __restrict__ hid, const float* __restrict__ Wh, ushort* __restrict__ EHb,
    const float* __restrict__ ctx, const float* __restrict__ Wc, ushort* __restrict__ ECb) {
  __shared__ ushort Xs[4096];
  __shared__ ushort Ws[4096];
  const int tid = threadIdx.x;
  const int bid = ((blockIdx.x & 7) << 6) | (blockIdx.x >> 3);   // 512: bijective
  const int lb = bid & 255;
  const int n0 = (lb >> 2) << 6, m0 = (lb & 3) << 6;
  const float* X = (bid < 256) ? hid : ctx;
  const float* W = (bid < 256) ? Wh : Wc;

  floatx4 acc[2][2];
#pragma unroll
  for (int i = 0; i < 2; ++i)
#pragma unroll
    for (int j = 0; j < 2; ++j) acc[i][j] = (floatx4){0.f, 0.f, 0.f, 0.f};
  gemm_core(X, W, n0, m0, Xs, Ws, tid, acc);

  const int lane = tid & 63, wave = tid >> 6;
  const int wn = wave & 1, wm = wave >> 1;
  const int l15 = lane & 15, lhi = lane >> 4;
  ushort* Y = (bid < 256) ? EHb : ECb;
#pragma unroll
  for (int fi = 0; fi < 2; ++fi)
#pragma unroll
    for (int fj = 0; fj < 2; ++fj)
#pragma unroll
      for (int rr = 0; rr < 4; ++rr) {
        const int row = n0 + wn * 32 + fi * 16 + lhi * 4 + rr;
        const int col = m0 + wm * 32 + fj * 16 + l15;
        Y[(size_t)row * M_DIM + col] = bf1(__builtin_amdgcn_exp2f(K2LOG2E * acc[fi][fj][rr]));
      }
}

// ---------------------------------------------------------------------------
// k2: mixed launch, 1024 blocks, parity-interleaved:
//   even bid: CWT gemm job j=bid>>1 (512 jobs): CWT ((S,B),H) bf16 = ctx.Wa^T
//   odd bid:  scores job j=bid>>1 (512 jobs): softmax over S per (t0..t0+7, b)
// CWT (MFMA/VMEM pipes) hides under scores (trans pipe); 4 blocks/CU.
// ---------------------------------------------------------------------------
__global__ __launch_bounds__(256, 4) void mid_kernel(
    const float* __restrict__ ctx, const float* __restrict__ Wa, ushort* __restrict__ CWT,
    const ushort* __restrict__ EH, const ushort* __restrict__ EC,
    const float* __restrict__ wff, const float* __restrict__ ctx_mask,
    ushort* __restrict__ aws) {
  __shared__ __align__(16) char smem[35584];
  const int tid = threadIdx.x;

  if ((blockIdx.x & 1) == 0) {
    // ---- CWT gemm ----
    const int j = blockIdx.x >> 1;
    const int n0 = (j >> 3) << 6;         // (s,b) row tile
    const int m0 = (j & 7) << 6;          // h tile
    ushort* Xs = (ushort*)smem;
    ushort* Ws = (ushort*)(smem + 8192);
    floatx4 acc[2][2];
#pragma unroll
    for (int i = 0; i < 2; ++i)
#pragma unroll
      for (int jj = 0; jj < 2; ++jj) acc[i][jj] = (floatx4){0.f, 0.f, 0.f, 0.f};
    gemm_core(ctx, Wa, n0, m0, Xs, Ws, tid, acc);

    const int lane = tid & 63, wave = tid >> 6;
    const int wn = wave & 1, wm = wave >> 1;
    const int l15 = lane & 15, lhi = lane >> 4;
#pragma unroll
    for (int fi = 0; fi < 2; ++fi)
#pragma unroll
      for (int fj = 0; fj < 2; ++fj)
#pragma unroll
        for (int rr = 0; rr < 4; ++rr) {
          const int row = n0 + wn * 32 + fi * 16 + lhi * 4 + rr;
          const int col = m0 + wm * 32 + fj * 16 + l15;
          CWT[(size_t)row * H_DIM + col] = bf1(acc[fi][fj][rr]);
        }
    return;
  }

  // ---- scores + softmax ----
  // alpha(s) = softmax_s( -2 * sum_m w[m] * rcp(EH[t,b,m]*EC[s,b,m] + 1) )
  {
    float4 (*ec)[8][128] = (float4 (*)[8][128])(smem);          // 32768 B
    float4 (*eh)[8][8]   = (float4 (*)[8][8])(smem + 32768);    // 2048 B
    float4 (*wf)[8]      = (float4 (*)[8])(smem + 34816);       // 256 B
    float* msk           = (float*)(smem + 35072);              // 512 B
    const int j = blockIdx.x >> 1;
    const int b = j & 31;
    const int t0 = (j >> 5) << 3;
    const int tt = tid >> 6;
    const int st = tid & 63;
    const int sld = tid >> 1, shf = tid & 1;   // EC staging: row, 16-col half

    if (tid < S_DIM) msk[tid] = ctx_mask[(size_t)tid * B_DIM + b];

    uint4 recu0, recu1;
    uint2 rehu;
    float4 rwf;
#define SLOAD(C)                                                                \
  {                                                                             \
    const ushort* p = EC + ((size_t)sld * B_DIM + b) * M_DIM + ((C) << 5) + (shf << 4); \
    recu0 = ((const uint4*)p)[0];                                               \
    recu1 = ((const uint4*)p)[1];                                               \
    if (tid < 64)                                                               \
      rehu = *(const uint2*)(EH + ((size_t)(t0 + (tid >> 3)) * B_DIM + b) * M_DIM + ((C) << 5) + ((tid & 7) << 2)); \
    if (tid < 8) rwf = *(const float4*)(wff + ((C) << 5) + (tid << 2));         \
  }
#define SSTORE(BUF)                                                             \
  {                                                                             \
    const int qb = shf << 2;                                                    \
    ec[BUF][qb + 0][sld] = expand4(recu0.x, recu0.y);                           \
    ec[BUF][qb + 1][sld] = expand4(recu0.z, recu0.w);                           \
    ec[BUF][qb + 2][sld] = expand4(recu1.x, recu1.y);                           \
    ec[BUF][qb + 3][sld] = expand4(recu1.z, recu1.w);                           \
    if (tid < 64) eh[BUF][tid & 7][tid >> 3] = expand4(rehu.x, rehu.y);         \
    if (tid < 8) wf[BUF][tid] = rwf;                                            \
  }

    floatx4 acc[2][2];
#pragma unroll
    for (int i = 0; i < 2; ++i)
#pragma unroll
      for (int jj = 0; jj < 2; ++jj) acc[i][jj] = (floatx4){0.f, 0.f, 0.f, 0.f};

    SLOAD(0)
    SSTORE(0)
    __syncthreads();

    for (int c = 0; c < 8; ++c) {
      const int cur = c & 1;
      if (c < 7) SLOAD(c + 1)
#pragma unroll
      for (int q = 0; q < 8; ++q) {
        const float4 w4 = wf[cur][q];
        const float4 e0 = eh[cur][q][2 * tt], e1 = eh[cur][q][2 * tt + 1];
        const float4 c0 = ec[cur][q][st],     c1 = ec[cur][q][st + 64];
#define ACC1(A, E, Cc)                                                 \
  A[0] += w4.x * __builtin_amdgcn_rcpf(E.x * Cc.x + 1.f);              \
  A[1] += w4.y * __builtin_amdgcn_rcpf(E.y * Cc.y + 1.f);              \
  A[2] += w4.z * __builtin_amdgcn_rcpf(E.z * Cc.z + 1.f);              \
  A[3] += w4.w * __builtin_amdgcn_rcpf(E.w * Cc.w + 1.f);
        ACC1(acc[0][0], e0, c0) ACC1(acc[0][1], e0, c1)
        ACC1(acc[1][0], e1, c0) ACC1(acc[1][1], e1, c1)
#undef ACC1
      }
      if (c < 7) {
        SSTORE(cur ^ 1)
        __syncthreads();
      }
    }
#undef SLOAD
#undef SSTORE

    const float mk0 = msk[st], mk1 = msk[st + 64];
    float sc[2][2];
#pragma unroll
    for (int ti = 0; ti < 2; ++ti) {
      const floatx4 a0 = acc[ti][0], a1 = acc[ti][1];
      sc[ti][0] = (mk0 > 0.f) ? -2.f * (a0[0] + a0[1] + a0[2] + a0[3]) : NEG_BIG;
      sc[ti][1] = (mk1 > 0.f) ? -2.f * (a1[0] + a1[1] + a1[2] + a1[3]) : NEG_BIG;
    }
#pragma unroll
    for (int ti = 0; ti < 2; ++ti) {
      float mx = fmaxf(sc[ti][0], sc[ti][1]);
#pragma unroll
      for (int off = 32; off > 0; off >>= 1) mx = fmaxf(mx, __shfl_xor(mx, off));
      const float e0 = __expf(sc[ti][0] - mx), e1 = __expf(sc[ti][1] - mx);
      float sum = e0 + e1;
#pragma unroll
      for (int off = 32; off > 0; off >>= 1) sum += __shfl_xor(sum, off);
      const float rinv = 1.f / sum;
      ushort* w = aws + ((size_t)(t0 + 2 * tt + ti) * B_DIM + b) * S_DIM;
      w[st] = bf1(e0 * rinv);
      w[st + 64] = bf1(e1 * rinv);
    }
  }
}

// ---------------------------------------------------------------------------
// k3: merged epilogue (640 blocks):
//   bid [0,512):   z (T,B,H) = alpha_b (T,S) . CW_b (S,H), K = 128
//   bid [512,640): AWS bf16 (T,B,S) -> alpha_out f32 (T,S,B), one block per t
// ---------------------------------------------------------------------------
__global__ __launch_bounds__(256) void epilogue_kernel(
    const ushort* __restrict__ AWS, const ushort* __restrict__ CWT,
    float* __restrict__ z, float* __restrict__ aout) {
  __shared__ char smem[17408];
  const int tid = threadIdx.x;

  if (blockIdx.x >= 512) {
    // ---- alpha transpose: AWS bf16 (T,B,S) -> aout f32 (T,S,B) ----
    float (*al)[129] = (float(*)[129])smem;
    const int t = blockIdx.x - 512;
    {
      const int b_ = tid >> 3, q = tid & 7;
      const ushort* src = AWS + ((size_t)t * B_DIM + b_) * S_DIM + q * 16;
      const uint4 u0 = ((const uint4*)src)[0];
      const uint4 u1 = ((const uint4*)src)[1];
      *(float4*)&al[b_][q * 16 + 0]  = expand4(u0.x, u0.y);
      *(float4*)&al[b_][q * 16 + 4]  = expand4(u0.z, u0.w);
      *(float4*)&al[b_][q * 16 + 8]  = expand4(u1.x, u1.y);
      *(float4*)&al[b_][q * 16 + 12] = expand4(u1.z, u1.w);
    }
    __syncthreads();
    {
      const int s = tid >> 1, half = tid & 1;
      float* dst = aout + ((size_t)t * S_DIM + s) * B_DIM + half * 16;
#pragma unroll
      for (int i = 0; i < 4; ++i) {
        float4 o;
        o.x = al[half * 16 + i * 4 + 0][s];
        o.y = al[half * 16 + i * 4 + 1][s];
        o.z = al[half * 16 + i * 4 + 2][s];
        o.w = al[half * 16 + i * 4 + 3][s];
        ((float4*)dst)[i] = o;
      }
    }
    return;
  }

  // ---- zgemm ----
  ushort* Xs = (ushort*)smem;                 // 4096 ushorts (8 KB)
  ushort* WsT = (ushort*)(smem + 8192);       // 64*72 ushorts (9 KB), [h][s]
  const int bid = blockIdx.x;
  const int m0 = (bid & 7) << 6;              // h
  const int n0 = ((bid >> 3) & 1) << 6;       // t
  const int b = bid >> 4;
  const int lane = tid & 63, wave = tid >> 6;
  const int wn = wave & 1, wm = wave >> 1;
  const int l15 = lane & 15, lhi = lane >> 4;
  const int r = tid >> 3, c8 = tid & 7;       // X staging
  const int lr = tid & 63, ls = tid >> 6;     // W staging (scatter)
  const int sw0 = (c8 ^ (r & 7)) << 4;
  char* xr0 = (char*)Xs + r * 128 + sw0;
  char* xr1 = (char*)Xs + (r + 32) * 128 + sw0;

  // Preload both K-halves (K=128 -> 2 iters of 64). AWS is bf16.
  uint4 xau[2], xbu[2];
  uint4 wv[2][2];
#pragma unroll
  for (int it = 0; it < 2; ++it) {
    xau[it] = *(const uint4*)(AWS + ((size_t)(n0 + r) * B_DIM + b) * S_DIM + it * 64 + c8 * 8);
    xbu[it] = *(const uint4*)(AWS + ((size_t)(n0 + r + 32) * B_DIM + b) * S_DIM + it * 64 + c8 * 8);
    const ushort* q = CWT + ((size_t)(it * 64 + lr) * B_DIM + b) * H_DIM + m0 + ls * 8;
    wv[it][0] = *(const uint4*)q;
    wv[it][1] = *(const uint4*)(q + 32);
  }

  floatx4 acc[2][2];
#pragma unroll
  for (int i = 0; i < 2; ++i)
#pragma unroll
    for (int j = 0; j < 2; ++j) acc[i][j] = (floatx4){0.f, 0.f, 0.f, 0.f};

#pragma unroll
  for (int it = 0; it < 2; ++it) {
    __syncthreads();
    *(uint4*)xr0 = xau[it];
    *(uint4*)xr1 = xbu[it];
#pragma unroll
    for (int q = 0; q < 2; ++q) {
      const int hb = ls * 8 + q * 32;          // h offset within tile
      const ushort* vs = (const ushort*)&wv[it][q];
#pragma unroll
      for (int i = 0; i < 8; ++i) WsT[(hb + i) * 72 + lr] = vs[i];
    }
    __syncthreads();
#pragma unroll
    for (int ks = 0; ks < 2; ++ks) {
      const int slot = lhi + (ks << 2);
      shortx8 af[2], bfr[2];
#pragma unroll
      for (int fi = 0; fi < 2; ++fi) {
        const int row = wn * 32 + fi * 16 + l15;
        af[fi] = *(const shortx8*)((const char*)Xs + row * 128 + ((slot ^ (row & 7)) << 4));
      }
#pragma unroll
      for (int fj = 0; fj < 2; ++fj) {
        const int col = wm * 32 + fj * 16 + l15;
        bfr[fj] = *(const shortx8*)((const char*)WsT + col * 144 + (slot << 4));
      }
#pragma unroll
      for (int fi = 0; fi < 2; ++fi)
#pragma unroll
        for (int fj = 0; fj < 2; ++fj)
          acc[fi][fj] = __builtin_amdgcn_mfma_f32_16x16x32_bf16(af[fi], bfr[fj], acc[fi][fj], 0, 0, 0);
    }
  }

#pragma unroll
  for (int fi = 0; fi < 2; ++fi)
#pragma unroll
    for (int fj = 0; fj < 2; ++fj)
#pragma unroll
      for (int r2 = 0; r2 < 4; ++r2) {
        const int t = n0 + wn * 32 + fi * 16 + lhi * 4 + r2;
        const int h = m0 + wm * 32 + fj * 16 + l15;
        z[((size_t)t * B_DIM + b) * H_DIM + h] = acc[fi][fj][r2];
      }
}

// ---------------------------------------------------------------------------
extern "C" void kernel_launch(void* const* d_in, const int* in_sizes, int n_in,
                              void* d_out, int out_size, void* d_ws, size_t ws_size,
                              hipStream_t stream) {
  const float* hid       = (const float*)d_in[0];   // (T,B,H)
  const float* ctx       = (const float*)d_in[1];   // (S,B,C)
  const float* ctx_mask  = (const float*)d_in[2];   // (S,B)
  const float* W_hid2mid = (const float*)d_in[3];   // (M,H)
  const float* W_ctx2mid = (const float*)d_in[4];   // (M,C)
  const float* w_ff      = (const float*)d_in[5];   // (M,)
  const float* W_att2hid = (const float*)d_in[6];   // (H,C)
  float* out = (float*)d_out;
  char*  ws  = (char*)d_ws;

  const size_t MB = 1 << 20;
  ushort* EHb = (ushort*)(ws);            // (T*B, M) bf16, 2 MB
  ushort* ECb = (ushort*)(ws + 2 * MB);   // (S*B, M) bf16, 2 MB
  ushort* AWS = (ushort*)(ws + 4 * MB);   // (T,B,S) bf16, 1 MB
  ushort* CWT = (ushort*)(ws + 5 * MB);   // ((S,B),H) bf16, 4 MB
  float* alpha_out = out;                               // (T,S,B)
  float* z_out     = out + T_DIM * S_DIM * B_DIM;       // (T,B,H)

  dim3 blk(256);
  // k1: EHb = exp(2*hid.Wh^T), ECb = exp(2*ctx.Wc^T)
  gemm_ehec<<<512, blk, 0, stream>>>(hid, W_hid2mid, EHb, ctx, W_ctx2mid, ECb);
  // k2: CWT = ctx.Wa^T (even bids) interleaved with scores+softmax (odd bids)
  mid_kernel<<<1024, blk, 0, stream>>>(ctx, W_att2hid, CWT, EHb, ECb,
                                       w_ff, ctx_mask, AWS);
  // k3: z-GEMM + alpha transpose
  epilogue_kernel<<<640, blk, 0, stream>>>(AWS, CWT, z_out, alpha_out);
}

// Round 18
// 59.355 us; speedup vs baseline: 3.2456x; 3.2456x over previous
//
#include <hip/hip_runtime.h>
#include <hip/hip_bf16.h>

#define T_DIM 128
#define S_DIM 128
#define B_DIM 32
#define H_DIM 512
#define C_DIM 512
#define M_DIM 256
#define NEG_BIG -1e8f
#define K2LOG2E 2.8853900817779268f   // 2*log2(e): exp(2x) = exp2(K*x)

typedef __attribute__((ext_vector_type(8))) short shortx8;   // 8 bf16
typedef __attribute__((ext_vector_type(4))) float floatx4;

// f32 -> bf16 RNE, packed pair
__device__ __forceinline__ unsigned bfpair(float a, float b) {
  unsigned ua = __builtin_bit_cast(unsigned, a); ua += 0x7fffu + ((ua >> 16) & 1u);
  unsigned ub = __builtin_bit_cast(unsigned, b); ub += 0x7fffu + ((ub >> 16) & 1u);
  return (ua >> 16) | (ub & 0xffff0000u);
}
__device__ __forceinline__ uint4 pack2(const float4& a, const float4& b) {
  uint4 o;
  o.x = bfpair(a.x, a.y); o.y = bfpair(a.z, a.w);
  o.z = bfpair(b.x, b.y); o.w = bfpair(b.z, b.w);
  return o;
}
__device__ __forceinline__ ushort bf1(float a) {
  unsigned ua = __builtin_bit_cast(unsigned, a); ua += 0x7fffu + ((ua >> 16) & 1u);
  return (ushort)(ua >> 16);
}
// bf16 (packed pair) -> f32 expansion
__device__ __forceinline__ float bflo(unsigned u) { return __builtin_bit_cast(float, u << 16); }
__device__ __forceinline__ float bfhi(unsigned u) { return __builtin_bit_cast(float, u & 0xffff0000u); }
__device__ __forceinline__ float4 expand4(unsigned a, unsigned b) {
  return make_float4(bflo(a), bfhi(a), bflo(b), bfhi(b));
}

// ---------------------------------------------------------------------------
// 64x64 MFMA tile job core, K=512, f32 operands packed to bf16 inline during
// LDS staging. r6-proven: single LDS buffer, 2 barriers per K-step, register
// prefetch between them, coalesced staging, XOR slot swizzle.
// ---------------------------------------------------------------------------
__device__ __forceinline__ void gemm_core(
    const float* __restrict__ X, const float* __restrict__ W,
    int n0, int m0, ushort* Xs, ushort* Ws, int tid, floatx4 acc[2][2]) {
  const int lane = tid & 63, wave = tid >> 6;
  const int wn = wave & 1, wm = wave >> 1;
  const int l15 = lane & 15, lhi = lane >> 4;
  const int r = tid >> 3, c8 = tid & 7;
  const int sw = (c8 ^ (r & 7)) << 4;         // (r+32)&7 == r&7
  char* xd0 = (char*)Xs + r * 128 + sw;
  char* xd1 = (char*)Xs + (r + 32) * 128 + sw;
  char* wd0 = (char*)Ws + r * 128 + sw;
  char* wd1 = (char*)Ws + (r + 32) * 128 + sw;

  const float* xp0 = X + (size_t)(n0 + r) * 512 + c8 * 8;
  const float* xp1 = X + (size_t)(n0 + r + 32) * 512 + c8 * 8;
  const float* wp0 = W + (size_t)(m0 + r) * 512 + c8 * 8;
  const float* wp1 = W + (size_t)(m0 + r + 32) * 512 + c8 * 8;

  float4 xf0, xf1, xf2, xf3, wf0, wf1, wf2, wf3;
#define LOADXW                                                  \
  xf0 = ((const float4*)xp0)[0]; xf1 = ((const float4*)xp0)[1]; \
  xf2 = ((const float4*)xp1)[0]; xf3 = ((const float4*)xp1)[1]; \
  wf0 = ((const float4*)wp0)[0]; wf1 = ((const float4*)wp0)[1]; \
  wf2 = ((const float4*)wp1)[0]; wf3 = ((const float4*)wp1)[1];
  LOADXW

  for (int it = 0; it < 8; ++it) {
    __syncthreads();   // previous tile's readers done
    *(uint4*)xd0 = pack2(xf0, xf1);
    *(uint4*)xd1 = pack2(xf2, xf3);
    *(uint4*)wd0 = pack2(wf0, wf1);
    *(uint4*)wd1 = pack2(wf2, wf3);
    __syncthreads();
    if (it < 7) {      // prefetch next K-tile; latency hides under MFMA
      xp0 += 64; xp1 += 64; wp0 += 64; wp1 += 64;
      LOADXW
    }
#pragma unroll
    for (int ks = 0; ks < 2; ++ks) {
      const int slotr = lhi + (ks << 2);
      const int sws = ((slotr ^ (l15 & 7)) << 4);
      shortx8 af[2], bfr[2];
#pragma unroll
      for (int fi = 0; fi < 2; ++fi)
        af[fi] = *(const shortx8*)((const char*)Xs + (wn * 32 + fi * 16 + l15) * 128 + sws);
#pragma unroll
      for (int fj = 0; fj < 2; ++fj)
        bfr[fj] = *(const shortx8*)((const char*)Ws + (wm * 32 + fj * 16 + l15) * 128 + sws);
#pragma unroll
      for (int fi = 0; fi < 2; ++fi)
#pragma unroll
        for (int fj = 0; fj < 2; ++fj)
          acc[fi][fj] = __builtin_amdgcn_mfma_f32_16x16x32_bf16(af[fi], bfr[fj], acc[fi][fj], 0, 0, 0);
    }
  }
#undef LOADXW
}

// ---------------------------------------------------------------------------
// k1: EH/EC only (512 blocks, XCD-swizzled):
//   bid [0,256):  EHb (T*B,M) bf16 = exp(2 * hid . Wh^T)
//   bid [256,512): ECb (S*B,M) bf16 = exp(2 * ctx . Wc^T)
// ---------------------------------------------------------------------------
__global__ __launch_bounds__(256) void gemm_ehec(
    const float* __restrict__ hid, const float* __restrict__ Wh, ushort* __restrict__ EHb,
    const float* __restrict__ ctx, const float* __restrict__ Wc, ushort* __restrict__ ECb) {
  __shared__ ushort Xs[4096];
  __shared__ ushort Ws[4096];
  const int tid = threadIdx.x;
  const int bid = ((blockIdx.x & 7) << 6) | (blockIdx.x >> 3);   // 512: bijective
  const int lb = bid & 255;
  const int n0 = (lb >> 2) << 6, m0 = (lb & 3) << 6;
  const float* X = (bid < 256) ? hid : ctx;
  const float* W = (bid < 256) ? Wh : Wc;

  floatx4 acc[2][2];
#pragma unroll
  for (int i = 0; i < 2; ++i)
#pragma unroll
    for (int j = 0; j < 2; ++j) acc[i][j] = (floatx4){0.f, 0.f, 0.f, 0.f};
  gemm_core(X, W, n0, m0, Xs, Ws, tid, acc);

  const int lane = tid & 63, wave = tid >> 6;
  const int wn = wave & 1, wm = wave >> 1;
  const int l15 = lane & 15, lhi = lane >> 4;
  ushort* Y = (bid < 256) ? EHb : ECb;
#pragma unroll
  for (int fi = 0; fi < 2; ++fi)
#pragma unroll
    for (int fj = 0; fj < 2; ++fj)
#pragma unroll
      for (int rr = 0; rr < 4; ++rr) {
        const int row = n0 + wn * 32 + fi * 16 + lhi * 4 + rr;
        const int col = m0 + wm * 32 + fj * 16 + l15;
        Y[(size_t)row * M_DIM + col] = bf1(__builtin_amdgcn_exp2f(K2LOG2E * acc[fi][fj][rr]));
      }
}

// ---------------------------------------------------------------------------
// k2: mixed launch, 1024 blocks, parity-interleaved (NO min-waves bound —
// r17's __launch_bounds__(256,4) capped VGPR at 64 and spilled 583 MB of
// scratch traffic; LDS 35.8 KB already yields 4 blocks/CU):
//   even bid: CWT gemm job j=bid>>1: CWT ((S,B),H) bf16 = ctx.Wa^T
//   odd bid:  scores job j=bid>>1: softmax over S per (t0..t0+7, b)
// CWT (MFMA/VMEM pipes) hides under scores (trans pipe).
// ---------------------------------------------------------------------------
__global__ __launch_bounds__(256) void mid_kernel(
    const float* __restrict__ ctx, const float* __restrict__ Wa, ushort* __restrict__ CWT,
    const ushort* __restrict__ EH, const ushort* __restrict__ EC,
    const float* __restrict__ wff, const float* __restrict__ ctx_mask,
    ushort* __restrict__ aws) {
  __shared__ __align__(16) char smem[35584];
  const int tid = threadIdx.x;

  if ((blockIdx.x & 1) == 0) {
    // ---- CWT gemm ----
    const int j = blockIdx.x >> 1;
    const int n0 = (j >> 3) << 6;         // (s,b) row tile
    const int m0 = (j & 7) << 6;          // h tile
    ushort* Xs = (ushort*)smem;
    ushort* Ws = (ushort*)(smem + 8192);
    floatx4 acc[2][2];
#pragma unroll
    for (int i = 0; i < 2; ++i)
#pragma unroll
      for (int jj = 0; jj < 2; ++jj) acc[i][jj] = (floatx4){0.f, 0.f, 0.f, 0.f};
    gemm_core(ctx, Wa, n0, m0, Xs, Ws, tid, acc);

    const int lane = tid & 63, wave = tid >> 6;
    const int wn = wave & 1, wm = wave >> 1;
    const int l15 = lane & 15, lhi = lane >> 4;
#pragma unroll
    for (int fi = 0; fi < 2; ++fi)
#pragma unroll
      for (int fj = 0; fj < 2; ++fj)
#pragma unroll
        for (int rr = 0; rr < 4; ++rr) {
          const int row = n0 + wn * 32 + fi * 16 + lhi * 4 + rr;
          const int col = m0 + wm * 32 + fj * 16 + l15;
          CWT[(size_t)row * H_DIM + col] = bf1(acc[fi][fj][rr]);
        }
    return;
  }

  // ---- scores + softmax ----
  // alpha(s) = softmax_s( -2 * sum_m w[m] * rcp(EH[t,b,m]*EC[s,b,m] + 1) )
  {
    float4 (*ec)[8][128] = (float4 (*)[8][128])(smem);          // 32768 B
    float4 (*eh)[8][8]   = (float4 (*)[8][8])(smem + 32768);    // 2048 B
    float4 (*wf)[8]      = (float4 (*)[8])(smem + 34816);       // 256 B
    float* msk           = (float*)(smem + 35072);              // 512 B
    const int j = blockIdx.x >> 1;
    const int b = j & 31;
    const int t0 = (j >> 5) << 3;
    const int tt = tid >> 6;
    const int st = tid & 63;
    const int sld = tid >> 1, shf = tid & 1;   // EC staging: row, 16-col half

    if (tid < S_DIM) msk[tid] = ctx_mask[(size_t)tid * B_DIM + b];

    uint4 recu0, recu1;
    uint2 rehu;
    float4 rwf;
#define SLOAD(C)                                                                \
  {                                                                             \
    const ushort* p = EC + ((size_t)sld * B_DIM + b) * M_DIM + ((C) << 5) + (shf << 4); \
    recu0 = ((const uint4*)p)[0];                                               \
    recu1 = ((const uint4*)p)[1];                                               \
    if (tid < 64)                                                               \
      rehu = *(const uint2*)(EH + ((size_t)(t0 + (tid >> 3)) * B_DIM + b) * M_DIM + ((C) << 5) + ((tid & 7) << 2)); \
    if (tid < 8) rwf = *(const float4*)(wff + ((C) << 5) + (tid << 2));         \
  }
#define SSTORE(BUF)                                                             \
  {                                                                             \
    const int qb = shf << 2;                                                    \
    ec[BUF][qb + 0][sld] = expand4(recu0.x, recu0.y);                           \
    ec[BUF][qb + 1][sld] = expand4(recu0.z, recu0.w);                           \
    ec[BUF][qb + 2][sld] = expand4(recu1.x, recu1.y);                           \
    ec[BUF][qb + 3][sld] = expand4(recu1.z, recu1.w);                           \
    if (tid < 64) eh[BUF][tid & 7][tid >> 3] = expand4(rehu.x, rehu.y);         \
    if (tid < 8) wf[BUF][tid] = rwf;                                            \
  }

    floatx4 acc[2][2];
#pragma unroll
    for (int i = 0; i < 2; ++i)
#pragma unroll
      for (int jj = 0; jj < 2; ++jj) acc[i][jj] = (floatx4){0.f, 0.f, 0.f, 0.f};

    SLOAD(0)
    SSTORE(0)
    __syncthreads();

    for (int c = 0; c < 8; ++c) {
      const int cur = c & 1;
      if (c < 7) SLOAD(c + 1)
#pragma unroll
      for (int q = 0; q < 8; ++q) {
        const float4 w4 = wf[cur][q];
        const float4 e0 = eh[cur][q][2 * tt], e1 = eh[cur][q][2 * tt + 1];
        const float4 c0 = ec[cur][q][st],     c1 = ec[cur][q][st + 64];
#define ACC1(A, E, Cc)                                                 \
  A[0] += w4.x * __builtin_amdgcn_rcpf(E.x * Cc.x + 1.f);              \
  A[1] += w4.y * __builtin_amdgcn_rcpf(E.y * Cc.y + 1.f);              \
  A[2] += w4.z * __builtin_amdgcn_rcpf(E.z * Cc.z + 1.f);              \
  A[3] += w4.w * __builtin_amdgcn_rcpf(E.w * Cc.w + 1.f);
        ACC1(acc[0][0], e0, c0) ACC1(acc[0][1], e0, c1)
        ACC1(acc[1][0], e1, c0) ACC1(acc[1][1], e1, c1)
#undef ACC1
      }
      if (c < 7) {
        SSTORE(cur ^ 1)
        __syncthreads();
      }
    }
#undef SLOAD
#undef SSTORE

    const float mk0 = msk[st], mk1 = msk[st + 64];
    float sc[2][2];
#pragma unroll
    for (int ti = 0; ti < 2; ++ti) {
      const floatx4 a0 = acc[ti][0], a1 = acc[ti][1];
      sc[ti][0] = (mk0 > 0.f) ? -2.f * (a0[0] + a0[1] + a0[2] + a0[3]) : NEG_BIG;
      sc[ti][1] = (mk1 > 0.f) ? -2.f * (a1[0] + a1[1] + a1[2] + a1[3]) : NEG_BIG;
    }
#pragma unroll
    for (int ti = 0; ti < 2; ++ti) {
      float mx = fmaxf(sc[ti][0], sc[ti][1]);
#pragma unroll
      for (int off = 32; off > 0; off >>= 1) mx = fmaxf(mx, __shfl_xor(mx, off));
      const float e0 = __expf(sc[ti][0] - mx), e1 = __expf(sc[ti][1] - mx);
      float sum = e0 + e1;
#pragma unroll
      for (int off = 32; off > 0; off >>= 1) sum += __shfl_xor(sum, off);
      const float rinv = 1.f / sum;
      ushort* w = aws + ((size_t)(t0 + 2 * tt + ti) * B_DIM + b) * S_DIM;
      w[st] = bf1(e0 * rinv);
      w[st + 64] = bf1(e1 * rinv);
    }
  }
}

// ---------------------------------------------------------------------------
// k3: merged epilogue (640 blocks):
//   bid [0,512):   z (T,B,H) = alpha_b (T,S) . CW_b (S,H), K = 128
//   bid [512,640): AWS bf16 (T,B,S) -> alpha_out f32 (T,S,B), one block per t
// ---------------------------------------------------------------------------
__global__ __launch_bounds__(256) void epilogue_kernel(
    const ushort* __restrict__ AWS, const ushort* __restrict__ CWT,
    float* __restrict__ z, float* __restrict__ aout) {
  __shared__ char smem[17408];
  const int tid = threadIdx.x;

  if (blockIdx.x >= 512) {
    // ---- alpha transpose: AWS bf16 (T,B,S) -> aout f32 (T,S,B) ----
    float (*al)[129] = (float(*)[129])smem;
    const int t = blockIdx.x - 512;
    {
      const int b_ = tid >> 3, q = tid & 7;
      const ushort* src = AWS + ((size_t)t * B_DIM + b_) * S_DIM + q * 16;
      const uint4 u0 = ((const uint4*)src)[0];
      const uint4 u1 = ((const uint4*)src)[1];
      *(float4*)&al[b_][q * 16 + 0]  = expand4(u0.x, u0.y);
      *(float4*)&al[b_][q * 16 + 4]  = expand4(u0.z, u0.w);
      *(float4*)&al[b_][q * 16 + 8]  = expand4(u1.x, u1.y);
      *(float4*)&al[b_][q * 16 + 12] = expand4(u1.z, u1.w);
    }
    __syncthreads();
    {
      const int s = tid >> 1, half = tid & 1;
      float* dst = aout + ((size_t)t * S_DIM + s) * B_DIM + half * 16;
#pragma unroll
      for (int i = 0; i < 4; ++i) {
        float4 o;
        o.x = al[half * 16 + i * 4 + 0][s];
        o.y = al[half * 16 + i * 4 + 1][s];
        o.z = al[half * 16 + i * 4 + 2][s];
        o.w = al[half * 16 + i * 4 + 3][s];
        ((float4*)dst)[i] = o;
      }
    }
    return;
  }

  // ---- zgemm ----
  ushort* Xs = (ushort*)smem;                 // 4096 ushorts (8 KB)
  ushort* WsT = (ushort*)(smem + 8192);       // 64*72 ushorts (9 KB), [h][s]
  const int bid = blockIdx.x;
  const int m0 = (bid & 7) << 6;              // h
  const int n0 = ((bid >> 3) & 1) << 6;       // t
  const int b = bid >> 4;
  const int lane = tid & 63, wave = tid >> 6;
  const int wn = wave & 1, wm = wave >> 1;
  const int l15 = lane & 15, lhi = lane >> 4;
  const int r = tid >> 3, c8 = tid & 7;       // X staging
  const int lr = tid & 63, ls = tid >> 6;     // W staging (scatter)
  const int sw0 = (c8 ^ (r & 7)) << 4;
  char* xr0 = (char*)Xs + r * 128 + sw0;
  char* xr1 = (char*)Xs + (r + 32) * 128 + sw0;

  // Preload both K-halves (K=128 -> 2 iters of 64). AWS is bf16.
  uint4 xau[2], xbu[2];
  uint4 wv[2][2];
#pragma unroll
  for (int it = 0; it < 2; ++it) {
    xau[it] = *(const uint4*)(AWS + ((size_t)(n0 + r) * B_DIM + b) * S_DIM + it * 64 + c8 * 8);
    xbu[it] = *(const uint4*)(AWS + ((size_t)(n0 + r + 32) * B_DIM + b) * S_DIM + it * 64 + c8 * 8);
    const ushort* q = CWT + ((size_t)(it * 64 + lr) * B_DIM + b) * H_DIM + m0 + ls * 8;
    wv[it][0] = *(const uint4*)q;
    wv[it][1] = *(const uint4*)(q + 32);
  }

  floatx4 acc[2][2];
#pragma unroll
  for (int i = 0; i < 2; ++i)
#pragma unroll
    for (int j = 0; j < 2; ++j) acc[i][j] = (floatx4){0.f, 0.f, 0.f, 0.f};

#pragma unroll
  for (int it = 0; it < 2; ++it) {
    __syncthreads();
    *(uint4*)xr0 = xau[it];
    *(uint4*)xr1 = xbu[it];
#pragma unroll
    for (int q = 0; q < 2; ++q) {
      const int hb = ls * 8 + q * 32;          // h offset within tile
      const ushort* vs = (const ushort*)&wv[it][q];
#pragma unroll
      for (int i = 0; i < 8; ++i) WsT[(hb + i) * 72 + lr] = vs[i];
    }
    __syncthreads();
#pragma unroll
    for (int ks = 0; ks < 2; ++ks) {
      const int slot = lhi + (ks << 2);
      shortx8 af[2], bfr[2];
#pragma unroll
      for (int fi = 0; fi < 2; ++fi) {
        const int row = wn * 32 + fi * 16 + l15;
        af[fi] = *(const shortx8*)((const char*)Xs + row * 128 + ((slot ^ (row & 7)) << 4));
      }
#pragma unroll
      for (int fj = 0; fj < 2; ++fj) {
        const int col = wm * 32 + fj * 16 + l15;
        bfr[fj] = *(const shortx8*)((const char*)WsT + col * 144 + (slot << 4));
      }
#pragma unroll
      for (int fi = 0; fi < 2; ++fi)
#pragma unroll
        for (int fj = 0; fj < 2; ++fj)
          acc[fi][fj] = __builtin_amdgcn_mfma_f32_16x16x32_bf16(af[fi], bfr[fj], acc[fi][fj], 0, 0, 0);
    }
  }

#pragma unroll
  for (int fi = 0; fi < 2; ++fi)
#pragma unroll
    for (int fj = 0; fj < 2; ++fj)
#pragma unroll
      for (int r2 = 0; r2 < 4; ++r2) {
        const int t = n0 + wn * 32 + fi * 16 + lhi * 4 + r2;
        const int h = m0 + wm * 32 + fj * 16 + l15;
        z[((size_t)t * B_DIM + b) * H_DIM + h] = acc[fi][fj][r2];
      }
}

// ---------------------------------------------------------------------------
extern "C" void kernel_launch(void* const* d_in, const int* in_sizes, int n_in,
                              void* d_out, int out_size, void* d_ws, size_t ws_size,
                              hipStream_t stream) {
  const float* hid       = (const float*)d_in[0];   // (T,B,H)
  const float* ctx       = (const float*)d_in[1];   // (S,B,C)
  const float* ctx_mask  = (const float*)d_in[2];   // (S,B)
  const float* W_hid2mid = (const float*)d_in[3];   // (M,H)
  const float* W_ctx2mid = (const float*)d_in[4];   // (M,C)
  const float* w_ff      = (const float*)d_in[5];   // (M,)
  const float* W_att2hid = (const float*)d_in[6];   // (H,C)
  float* out = (float*)d_out;
  char*  ws  = (char*)d_ws;

  const size_t MB = 1 << 20;
  ushort* EHb = (ushort*)(ws);            // (T*B, M) bf16, 2 MB
  ushort* ECb = (ushort*)(ws + 2 * MB);   // (S*B, M) bf16, 2 MB
  ushort* AWS = (ushort*)(ws + 4 * MB);   // (T,B,S) bf16, 1 MB
  ushort* CWT = (ushort*)(ws + 5 * MB);   // ((S,B),H) bf16, 4 MB
  float* alpha_out = out;                               // (T,S,B)
  float* z_out     = out + T_DIM * S_DIM * B_DIM;       // (T,B,H)

  dim3 blk(256);
  // k1: EHb = exp(2*hid.Wh^T), ECb = exp(2*ctx.Wc^T)
  gemm_ehec<<<512, blk, 0, stream>>>(hid, W_hid2mid, EHb, ctx, W_ctx2mid, ECb);
  // k2: CWT = ctx.Wa^T (even bids) interleaved with scores+softmax (odd bids)
  mid_kernel<<<1024, blk, 0, stream>>>(ctx, W_att2hid, CWT, EHb, ECb,
                                       w_ff, ctx_mask, AWS);
  // k3: z-GEMM + alpha transpose
  epilogue_kernel<<<640, blk, 0, stream>>>(AWS, CWT, z_out, alpha_out);
}

// Round 19
// 49.007 us; speedup vs baseline: 3.9309x; 1.2111x over previous
//
#include <hip/hip_runtime.h>
#include <hip/hip_bf16.h>

#define T_DIM 128
#define S_DIM 128
#define B_DIM 32
#define H_DIM 512
#define C_DIM 512
#define M_DIM 256
#define NEG_BIG -1e8f
#define K2LOG2E 2.8853900817779268f   // 2*log2(e): exp(2x) = exp2(K*x)

typedef __attribute__((ext_vector_type(8))) short shortx8;   // 8 bf16
typedef __attribute__((ext_vector_type(4))) float floatx4;

// f32 -> bf16 RNE, packed pair
__device__ __forceinline__ unsigned bfpair(float a, float b) {
  unsigned ua = __builtin_bit_cast(unsigned, a); ua += 0x7fffu + ((ua >> 16) & 1u);
  unsigned ub = __builtin_bit_cast(unsigned, b); ub += 0x7fffu + ((ub >> 16) & 1u);
  return (ua >> 16) | (ub & 0xffff0000u);
}
__device__ __forceinline__ uint4 pack2(const float4& a, const float4& b) {
  uint4 o;
  o.x = bfpair(a.x, a.y); o.y = bfpair(a.z, a.w);
  o.z = bfpair(b.x, b.y); o.w = bfpair(b.z, b.w);
  return o;
}
__device__ __forceinline__ ushort bf1(float a) {
  unsigned ua = __builtin_bit_cast(unsigned, a); ua += 0x7fffu + ((ua >> 16) & 1u);
  return (ushort)(ua >> 16);
}
// bf16 (packed pair) -> f32 expansion
__device__ __forceinline__ float bflo(unsigned u) { return __builtin_bit_cast(float, u << 16); }
__device__ __forceinline__ float bfhi(unsigned u) { return __builtin_bit_cast(float, u & 0xffff0000u); }
__device__ __forceinline__ float4 expand4(unsigned a, unsigned b) {
  return make_float4(bflo(a), bfhi(a), bflo(b), bfhi(b));
}

// ---------------------------------------------------------------------------
// One launch, three GEMM sets (all K=512, f32 inputs packed to bf16 inline
// during LDS staging), 64x64 tiles, BK=64, 1024 blocks, XCD-aware bid swizzle
// (each XCD's 128-job chunk touches <=4 MB of f32 panels -> L2-resident):
//   bid [0,256):    EHb (T*B,M) bf16 = exp(2 * hid . Wh^T)
//   bid [256,512):  ECb (S*B,M) bf16 = exp(2 * ctx . Wc^T)
//   bid [512,1024): CWT ((S,B),H) bf16 = ctx . Wa^T
// r6-proven core: single LDS buffer, 2 barriers per K-step, register
// prefetch between them, coalesced staging, XOR slot swizzle.
// ---------------------------------------------------------------------------
__global__ __launch_bounds__(256) void gemm_multi(
    const float* __restrict__ hid, const float* __restrict__ Wh, ushort* __restrict__ EHb,
    const float* __restrict__ ctx, const float* __restrict__ Wc, ushort* __restrict__ ECb,
    const float* __restrict__ Wa, ushort* __restrict__ CWT) {
  __shared__ ushort Xs[4096];
  __shared__ ushort Ws[4096];
  const int tid = threadIdx.x;
  // XCD swizzle: 8 XCDs x 128 contiguous jobs each -> per-XCD L2 panel reuse
  const int bid = ((blockIdx.x & 7) << 7) | (blockIdx.x >> 3);

  const float *X, *W;
  int n0, m0;
  if (bid < 512) {
    const int lb = bid & 255;
    n0 = (lb >> 2) << 6; m0 = (lb & 3) << 6;
    X = (bid < 256) ? hid : ctx;
    W = (bid < 256) ? Wh : Wc;
  } else {
    const int lb = bid - 512;
    n0 = (lb >> 3) << 6;          // (s,b) row tile
    m0 = (lb & 7) << 6;           // h tile
    X = ctx;
    W = Wa;
  }

  const int lane = tid & 63, wave = tid >> 6;
  const int wn = wave & 1, wm = wave >> 1;
  const int l15 = lane & 15, lhi = lane >> 4;
  const int r = tid >> 3, c8 = tid & 7;
  const int sw = (c8 ^ (r & 7)) << 4;         // (r+32)&7 == r&7
  char* xd0 = (char*)Xs + r * 128 + sw;
  char* xd1 = (char*)Xs + (r + 32) * 128 + sw;
  char* wd0 = (char*)Ws + r * 128 + sw;
  char* wd1 = (char*)Ws + (r + 32) * 128 + sw;

  const float* xp0 = X + (size_t)(n0 + r) * 512 + c8 * 8;
  const float* xp1 = X + (size_t)(n0 + r + 32) * 512 + c8 * 8;
  const float* wp0 = W + (size_t)(m0 + r) * 512 + c8 * 8;
  const float* wp1 = W + (size_t)(m0 + r + 32) * 512 + c8 * 8;

  float4 xf0, xf1, xf2, xf3, wf0, wf1, wf2, wf3;
#define LOADXW                                                  \
  xf0 = ((const float4*)xp0)[0]; xf1 = ((const float4*)xp0)[1]; \
  xf2 = ((const float4*)xp1)[0]; xf3 = ((const float4*)xp1)[1]; \
  wf0 = ((const float4*)wp0)[0]; wf1 = ((const float4*)wp0)[1]; \
  wf2 = ((const float4*)wp1)[0]; wf3 = ((const float4*)wp1)[1];
  LOADXW

  floatx4 acc[2][2];
#pragma unroll
  for (int i = 0; i < 2; ++i)
#pragma unroll
    for (int j = 0; j < 2; ++j) acc[i][j] = (floatx4){0.f, 0.f, 0.f, 0.f};

  for (int it = 0; it < 8; ++it) {
    __syncthreads();   // previous tile's readers done
    *(uint4*)xd0 = pack2(xf0, xf1);
    *(uint4*)xd1 = pack2(xf2, xf3);
    *(uint4*)wd0 = pack2(wf0, wf1);
    *(uint4*)wd1 = pack2(wf2, wf3);
    __syncthreads();
    if (it < 7) {      // prefetch next K-tile; latency hides under MFMA
      xp0 += 64; xp1 += 64; wp0 += 64; wp1 += 64;
      LOADXW
    }
#pragma unroll
    for (int ks = 0; ks < 2; ++ks) {
      const int slotr = lhi + (ks << 2);
      const int sws = ((slotr ^ (l15 & 7)) << 4);
      shortx8 af[2], bfr[2];
#pragma unroll
      for (int fi = 0; fi < 2; ++fi)
        af[fi] = *(const shortx8*)((const char*)Xs + (wn * 32 + fi * 16 + l15) * 128 + sws);
#pragma unroll
      for (int fj = 0; fj < 2; ++fj)
        bfr[fj] = *(const shortx8*)((const char*)Ws + (wm * 32 + fj * 16 + l15) * 128 + sws);
#pragma unroll
      for (int fi = 0; fi < 2; ++fi)
#pragma unroll
        for (int fj = 0; fj < 2; ++fj)
          acc[fi][fj] = __builtin_amdgcn_mfma_f32_16x16x32_bf16(af[fi], bfr[fj], acc[fi][fj], 0, 0, 0);
    }
  }
#undef LOADXW

  if (bid < 512) {
    ushort* Y = (bid < 256) ? EHb : ECb;
#pragma unroll
    for (int fi = 0; fi < 2; ++fi)
#pragma unroll
      for (int fj = 0; fj < 2; ++fj)
#pragma unroll
        for (int rr = 0; rr < 4; ++rr) {
          const int row = n0 + wn * 32 + fi * 16 + lhi * 4 + rr;
          const int col = m0 + wm * 32 + fj * 16 + l15;
          Y[(size_t)row * M_DIM + col] = bf1(__builtin_amdgcn_exp2f(K2LOG2E * acc[fi][fj][rr]));
        }
  } else {
#pragma unroll
    for (int fi = 0; fi < 2; ++fi)
#pragma unroll
      for (int fj = 0; fj < 2; ++fj)
#pragma unroll
        for (int rr = 0; rr < 4; ++rr) {
          const int row = n0 + wn * 32 + fi * 16 + lhi * 4 + rr;
          const int col = m0 + wm * 32 + fj * 16 + l15;
          CWT[(size_t)row * H_DIM + col] = bf1(acc[fi][fj][rr]);
        }
  }
}

// ---------------------------------------------------------------------------
// Fused scores + softmax, exp-factored:
//   alpha(s) = softmax_s( -2 * sum_m w[m] * rcp(EH[t,b,m]*EC[s,b,m] + 1) )
// EH/EC read as bf16, expanded to f32 during LDS staging. Block: 8 t-rows x
// full S, fixed b. Thread tile 2t x 2s. Double-buffered 32-m chunks.
// Writes AWS bf16 in (T,B,S) layout.
// ---------------------------------------------------------------------------
__global__ __launch_bounds__(256) void scores_kernel(
    const ushort* __restrict__ EH, const ushort* __restrict__ EC,
    const float* __restrict__ w_ff, const float* __restrict__ ctx_mask,
    ushort* __restrict__ aws) {
  __shared__ float4 ec[2][8][128];
  __shared__ float4 eh[2][8][8];
  __shared__ float4 wf[2][8];
  __shared__ float msk[S_DIM];
  const int tid = threadIdx.x;
  const int b = blockIdx.y;
  const int t0 = blockIdx.x << 3;
  const int tt = tid >> 6;
  const int st = tid & 63;
  const int sld = tid >> 1, shf = tid & 1;   // EC staging: row, 16-col half

  if (tid < S_DIM) msk[tid] = ctx_mask[(size_t)tid * B_DIM + b];

  uint4 recu0, recu1;
  uint2 rehu;
  float4 rwf;
#define SLOAD(C)                                                                \
  {                                                                             \
    const ushort* p = EC + ((size_t)sld * B_DIM + b) * M_DIM + ((C) << 5) + (shf << 4); \
    recu0 = ((const uint4*)p)[0];                                               \
    recu1 = ((const uint4*)p)[1];                                               \
    if (tid < 64)                                                               \
      rehu = *(const uint2*)(EH + ((size_t)(t0 + (tid >> 3)) * B_DIM + b) * M_DIM + ((C) << 5) + ((tid & 7) << 2)); \
    if (tid < 8) rwf = *(const float4*)(w_ff + ((C) << 5) + (tid << 2));        \
  }
#define SSTORE(BUF)                                                             \
  {                                                                             \
    const int qb = shf << 2;                                                    \
    ec[BUF][qb + 0][sld] = expand4(recu0.x, recu0.y);                           \
    ec[BUF][qb + 1][sld] = expand4(recu0.z, recu0.w);                           \
    ec[BUF][qb + 2][sld] = expand4(recu1.x, recu1.y);                           \
    ec[BUF][qb + 3][sld] = expand4(recu1.z, recu1.w);                           \
    if (tid < 64) eh[BUF][tid & 7][tid >> 3] = expand4(rehu.x, rehu.y);         \
    if (tid < 8) wf[BUF][tid] = rwf;                                            \
  }

  floatx4 acc[2][2];
#pragma unroll
  for (int i = 0; i < 2; ++i)
#pragma unroll
    for (int j = 0; j < 2; ++j) acc[i][j] = (floatx4){0.f, 0.f, 0.f, 0.f};

  SLOAD(0)
  SSTORE(0)
  __syncthreads();

  for (int c = 0; c < 8; ++c) {
    const int cur = c & 1;
    if (c < 7) SLOAD(c + 1)
#pragma unroll
    for (int q = 0; q < 8; ++q) {
      const float4 w4 = wf[cur][q];
      const float4 e0 = eh[cur][q][2 * tt], e1 = eh[cur][q][2 * tt + 1];
      const float4 c0 = ec[cur][q][st],     c1 = ec[cur][q][st + 64];
#define ACC1(A, E, Cc)                                                 \
  A[0] += w4.x * __builtin_amdgcn_rcpf(E.x * Cc.x + 1.f);              \
  A[1] += w4.y * __builtin_amdgcn_rcpf(E.y * Cc.y + 1.f);              \
  A[2] += w4.z * __builtin_amdgcn_rcpf(E.z * Cc.z + 1.f);              \
  A[3] += w4.w * __builtin_amdgcn_rcpf(E.w * Cc.w + 1.f);
      ACC1(acc[0][0], e0, c0) ACC1(acc[0][1], e0, c1)
      ACC1(acc[1][0], e1, c0) ACC1(acc[1][1], e1, c1)
#undef ACC1
    }
    if (c < 7) {
      SSTORE(cur ^ 1)
      __syncthreads();
    }
  }
#undef SLOAD
#undef SSTORE

  const float mk0 = msk[st], mk1 = msk[st + 64];
  float sc[2][2];
#pragma unroll
  for (int ti = 0; ti < 2; ++ti) {
    const floatx4 a0 = acc[ti][0], a1 = acc[ti][1];
    sc[ti][0] = (mk0 > 0.f) ? -2.f * (a0[0] + a0[1] + a0[2] + a0[3]) : NEG_BIG;
    sc[ti][1] = (mk1 > 0.f) ? -2.f * (a1[0] + a1[1] + a1[2] + a1[3]) : NEG_BIG;
  }
#pragma unroll
  for (int ti = 0; ti < 2; ++ti) {
    float mx = fmaxf(sc[ti][0], sc[ti][1]);
#pragma unroll
    for (int off = 32; off > 0; off >>= 1) mx = fmaxf(mx, __shfl_xor(mx, off));
    const float e0 = __expf(sc[ti][0] - mx), e1 = __expf(sc[ti][1] - mx);
    float sum = e0 + e1;
#pragma unroll
    for (int off = 32; off > 0; off >>= 1) sum += __shfl_xor(sum, off);
    const float rinv = 1.f / sum;
    ushort* w = aws + ((size_t)(t0 + 2 * tt + ti) * B_DIM + b) * S_DIM;
    w[st] = bf1(e0 * rinv);
    w[st + 64] = bf1(e1 * rinv);
  }
}

// ---------------------------------------------------------------------------
// Merged epilogue (one launch, 640 blocks):
//   bid [0,512):   z (T,B,H) = alpha_b (T,S) . CW_b (S,H), K = 128
//   bid [512,640): AWS bf16 (T,B,S) -> alpha_out f32 (T,S,B), one block per t
// ---------------------------------------------------------------------------
__global__ __launch_bounds__(256) void epilogue_kernel(
    const ushort* __restrict__ AWS, const ushort* __restrict__ CWT,
    float* __restrict__ z, float* __restrict__ aout) {
  __shared__ char smem[17408];
  const int tid = threadIdx.x;

  if (blockIdx.x >= 512) {
    // ---- alpha transpose: AWS bf16 (T,B,S) -> aout f32 (T,S,B) ----
    float (*al)[129] = (float(*)[129])smem;
    const int t = blockIdx.x - 512;
    {
      const int b_ = tid >> 3, q = tid & 7;
      const ushort* src = AWS + ((size_t)t * B_DIM + b_) * S_DIM + q * 16;
      const uint4 u0 = ((const uint4*)src)[0];
      const uint4 u1 = ((const uint4*)src)[1];
      *(float4*)&al[b_][q * 16 + 0]  = expand4(u0.x, u0.y);
      *(float4*)&al[b_][q * 16 + 4]  = expand4(u0.z, u0.w);
      *(float4*)&al[b_][q * 16 + 8]  = expand4(u1.x, u1.y);
      *(float4*)&al[b_][q * 16 + 12] = expand4(u1.z, u1.w);
    }
    __syncthreads();
    {
      const int s = tid >> 1, half = tid & 1;
      float* dst = aout + ((size_t)t * S_DIM + s) * B_DIM + half * 16;
#pragma unroll
      for (int i = 0; i < 4; ++i) {
        float4 o;
        o.x = al[half * 16 + i * 4 + 0][s];
        o.y = al[half * 16 + i * 4 + 1][s];
        o.z = al[half * 16 + i * 4 + 2][s];
        o.w = al[half * 16 + i * 4 + 3][s];
        ((float4*)dst)[i] = o;
      }
    }
    return;
  }

  // ---- zgemm ----
  ushort* Xs = (ushort*)smem;                 // 4096 ushorts (8 KB)
  ushort* WsT = (ushort*)(smem + 8192);       // 64*72 ushorts (9 KB), [h][s]
  const int bid = blockIdx.x;
  const int m0 = (bid & 7) << 6;              // h
  const int n0 = ((bid >> 3) & 1) << 6;       // t
  const int b = bid >> 4;
  const int lane = tid & 63, wave = tid >> 6;
  const int wn = wave & 1, wm = wave >> 1;
  const int l15 = lane & 15, lhi = lane >> 4;
  const int r = tid >> 3, c8 = tid & 7;       // X staging
  const int lr = tid & 63, ls = tid >> 6;     // W staging (scatter)
  const int sw0 = (c8 ^ (r & 7)) << 4;
  char* xr0 = (char*)Xs + r * 128 + sw0;
  char* xr1 = (char*)Xs + (r + 32) * 128 + sw0;

  // Preload both K-halves (K=128 -> 2 iters of 64). AWS is bf16.
  uint4 xau[2], xbu[2];
  uint4 wv[2][2];
#pragma unroll
  for (int it = 0; it < 2; ++it) {
    xau[it] = *(const uint4*)(AWS + ((size_t)(n0 + r) * B_DIM + b) * S_DIM + it * 64 + c8 * 8);
    xbu[it] = *(const uint4*)(AWS + ((size_t)(n0 + r + 32) * B_DIM + b) * S_DIM + it * 64 + c8 * 8);
    const ushort* q = CWT + ((size_t)(it * 64 + lr) * B_DIM + b) * H_DIM + m0 + ls * 8;
    wv[it][0] = *(const uint4*)q;
    wv[it][1] = *(const uint4*)(q + 32);
  }

  floatx4 acc[2][2];
#pragma unroll
  for (int i = 0; i < 2; ++i)
#pragma unroll
    for (int j = 0; j < 2; ++j) acc[i][j] = (floatx4){0.f, 0.f, 0.f, 0.f};

#pragma unroll
  for (int it = 0; it < 2; ++it) {
    __syncthreads();
    *(uint4*)xr0 = xau[it];
    *(uint4*)xr1 = xbu[it];
#pragma unroll
    for (int q = 0; q < 2; ++q) {
      const int hb = ls * 8 + q * 32;          // h offset within tile
      const ushort* vs = (const ushort*)&wv[it][q];
#pragma unroll
      for (int i = 0; i < 8; ++i) WsT[(hb + i) * 72 + lr] = vs[i];
    }
    __syncthreads();
#pragma unroll
    for (int ks = 0; ks < 2; ++ks) {
      const int slot = lhi + (ks << 2);
      shortx8 af[2], bfr[2];
#pragma unroll
      for (int fi = 0; fi < 2; ++fi) {
        const int row = wn * 32 + fi * 16 + l15;
        af[fi] = *(const shortx8*)((const char*)Xs + row * 128 + ((slot ^ (row & 7)) << 4));
      }
#pragma unroll
      for (int fj = 0; fj < 2; ++fj) {
        const int col = wm * 32 + fj * 16 + l15;
        bfr[fj] = *(const shortx8*)((const char*)WsT + col * 144 + (slot << 4));
      }
#pragma unroll
      for (int fi = 0; fi < 2; ++fi)
#pragma unroll
        for (int fj = 0; fj < 2; ++fj)
          acc[fi][fj] = __builtin_amdgcn_mfma_f32_16x16x32_bf16(af[fi], bfr[fj], acc[fi][fj], 0, 0, 0);
    }
  }

#pragma unroll
  for (int fi = 0; fi < 2; ++fi)
#pragma unroll
    for (int fj = 0; fj < 2; ++fj)
#pragma unroll
      for (int r2 = 0; r2 < 4; ++r2) {
        const int t = n0 + wn * 32 + fi * 16 + lhi * 4 + r2;
        const int h = m0 + wm * 32 + fj * 16 + l15;
        z[((size_t)t * B_DIM + b) * H_DIM + h] = acc[fi][fj][r2];
      }
}

// ---------------------------------------------------------------------------
extern "C" void kernel_launch(void* const* d_in, const int* in_sizes, int n_in,
                              void* d_out, int out_size, void* d_ws, size_t ws_size,
                              hipStream_t stream) {
  const float* hid       = (const float*)d_in[0];   // (T,B,H)
  const float* ctx       = (const float*)d_in[1];   // (S,B,C)
  const float* ctx_mask  = (const float*)d_in[2];   // (S,B)
  const float* W_hid2mid = (const float*)d_in[3];   // (M,H)
  const float* W_ctx2mid = (const float*)d_in[4];   // (M,C)
  const float* w_ff      = (const float*)d_in[5];   // (M,)
  const float* W_att2hid = (const float*)d_in[6];   // (H,C)
  float* out = (float*)d_out;
  char*  ws  = (char*)d_ws;

  const size_t MB = 1 << 20;
  ushort* EHb = (ushort*)(ws);            // (T*B, M) bf16, 2 MB
  ushort* ECb = (ushort*)(ws + 2 * MB);   // (S*B, M) bf16, 2 MB
  ushort* AWS = (ushort*)(ws + 4 * MB);   // (T,B,S) bf16, 1 MB
  ushort* CWT = (ushort*)(ws + 5 * MB);   // ((S,B),H) bf16, 4 MB
  float* alpha_out = out;                               // (T,S,B)
  float* z_out     = out + T_DIM * S_DIM * B_DIM;       // (T,B,H)

  dim3 blk(256);
  // EHb = exp(2*hid.Wh^T), ECb = exp(2*ctx.Wc^T), CWT = ctx.Wa^T (all bf16,
  // f32 inputs packed inline)
  gemm_multi<<<1024, blk, 0, stream>>>(hid, W_hid2mid, EHb, ctx, W_ctx2mid, ECb,
                                       W_att2hid, CWT);
  // fused tanh-scores + masked softmax -> AWS bf16 (T,B,S)
  scores_kernel<<<dim3(T_DIM / 8, B_DIM), blk, 0, stream>>>(EHb, ECb, w_ff, ctx_mask, AWS);
  // z-GEMM + alpha transpose, single launch
  epilogue_kernel<<<640, blk, 0, stream>>>(AWS, CWT, z_out, alpha_out);
}